// Round 14
// baseline (491.834 us; speedup 1.0000x reference)
//
#include <hip/hip_runtime.h>
#include <cstdint>
#include <cstddef>

typedef unsigned short u16;
typedef unsigned int   u32;
typedef __attribute__((ext_vector_type(8))) short bf16x8;
typedef __attribute__((ext_vector_type(4))) float f32x4;

#define NB   16
#define LL   1024
#define CIN  300
#define CINP 320              /* padded channels: rows 640B, 16B aligned */
#define XPBP (LL*CINP)        /* 327680 elems per batch */
#define XELP (NB*XPBP)        /* 5242880 */
#define NCH  6000
#define NCHP 6144             /* padded to 24*256 */
#define ODIM 100

#define BM 256
#define BN 256
#define BK 64

__device__ __forceinline__ u16 f2bf(float f) {
  union { float f; u32 u; } v; v.f = f;
  return (u16)((v.u + 0x7FFFu + ((v.u >> 16) & 1u)) >> 16);   // RNE, inputs finite
}

typedef __attribute__((address_space(1))) const unsigned int gu32;
typedef __attribute__((address_space(3))) unsigned int lu32;
__device__ __forceinline__ void gload_lds16(const void* g, void* l) {
  __builtin_amdgcn_global_load_lds((gu32*)g, (lu32*)l, 16, 0, 0);
}

#define BAR() asm volatile("s_barrier" ::: "memory")
#define VM4  asm volatile("s_waitcnt vmcnt(4)" ::: "memory")
#define VM2  asm volatile("s_waitcnt vmcnt(2)" ::: "memory")
#define VM0  asm volatile("s_waitcnt vmcnt(0)" ::: "memory")

// ---- merged prep: repack W (blocks 0..18431) + cvt x (blocks 18432..20991)
__global__ void prep_kernel(const float* __restrict__ x,
                            const float* __restrict__ W2, const float* __restrict__ W3,
                            const float* __restrict__ W4,
                            u16* __restrict__ xb, u16* __restrict__ wb) {
  int bid = blockIdx.x;
  if (bid < 3 * NCHP) {
    // W[n,o,c,j] f32 -> Wb[no][kp = j*320 + c] bf16 (zeros c>=300, no>=6000)
    int g  = bid / NCHP;
    int no = bid - g * NCHP;                   // 0..6143
    int kk = g + 2;
    int Kp = kk * CINP;
    int woff = (g == 0) ? 0 : (g == 1) ? NCHP*640 : NCHP*(640+960);
    const float* W = (g == 0) ? W2 : (g == 1) ? W3 : W4;
    u16* dst = wb + (size_t)woff + (size_t)no * Kp;
    const float* src = W + (size_t)no * (CIN * kk);
    for (int kp = threadIdx.x; kp < Kp; kp += 256) {
      int j = kp / CINP, c = kp - j * CINP;
      u16 v = 0;
      if (no < NCH && c < CIN) v = f2bf(src[c * kk + j]);
      dst[kp] = v;
    }
  } else {
    // x [16,1024,300] f32 -> xb [16,1024,320] bf16 (zero-pad channels)
    int i8 = ((bid - 3 * NCHP) * 256 + threadIdx.x) * 8;   // 2560 blocks
    int row = i8 / CINP;
    int col = i8 - row * CINP;
    const float* src = x + (size_t)row * CIN + col;
    u16 e[8];
    if (col + 8 <= CIN) {
      float4 a = *(const float4*)src;
      float4 b = *(const float4*)(src + 4);
      e[0]=f2bf(a.x); e[1]=f2bf(a.y); e[2]=f2bf(a.z); e[3]=f2bf(a.w);
      e[4]=f2bf(b.x); e[5]=f2bf(b.y); e[6]=f2bf(b.z); e[7]=f2bf(b.w);
    } else {
      #pragma unroll
      for (int j = 0; j < 8; j++)
        e[j] = (col + j < CIN) ? f2bf(src[j]) : (u16)0;
    }
    uint4 o;
    o.x = (u32)e[0] | ((u32)e[1] << 16);
    o.y = (u32)e[2] | ((u32)e[3] << 16);
    o.z = (u32)e[4] | ((u32)e[5] << 16);
    o.w = (u32)e[6] | ((u32)e[7] << 16);
    *(uint4*)(xb + i8) = o;
  }
}

// ---- fused GEMM + running-max + bias + relu ------------------------------
// 256^2 schedule, TWO barriers/K-step (r14). Regions: I=[ph1+ph2], II=[ph3+ph4].
// Per-wave DMA issue order per step: a0,b0 (region I) | b1,a1 (region II).
// Queue-tracked certification (entering region I: 2 outstanding = prev a1):
//   region-I-end  VM4+BAR: retires prev-a1 -> certifies cA-h1 for region II read
//                          (leaves a0,b0 in flight - no stall on fresh loads)
//   region-II-end VM2+BAR: retires a0,b0,b1 -> certifies next step's region-I
//                          start-reads (cA0,cB0,cB1); leaves a1.
// WAR at 1-region skew: region I writes nA-h0 (= cA(s-1) buffer, h0) while a
// skewed wave reads only h1 of that buffer; all other pairs opposite-parity.
__global__ __launch_bounds__(512, 1)
void gemm_max_kernel(const u16* __restrict__ xb, const u16* __restrict__ wb,
                     const float* __restrict__ b2v, const float* __restrict__ b3v,
                     const float* __restrict__ b4v, float* __restrict__ out) {
  // LPT remap: ids 0..383 -> g=2, 384..767 -> g=1, 768..1151 -> g=0
  const int id    = blockIdx.x;
  const int g     = 2 - (id / 384);
  const int id2   = id % 384;
  const int b     = id2 / 24;      // 0..15
  const int chblk = id2 % 24;      // 0..23
  const int Kp    = (g + 2) * CINP;                 // 640 / 960 / 1280
  const int nks   = Kp >> 6;                        // 10 / 15 / 20
  const int woff  = (g == 0) ? 0 : (g == 1) ? NCHP*640 : NCHP*(640+960);
  const int Lt    = LL - (g + 2) + 1;

  __shared__ __align__(16) u16 smem[4 * 16384];     // 128 KiB
  u16* A0s = smem;
  u16* B0s = smem + 16384;
  u16* A1s = smem + 32768;
  u16* B1s = smem + 49152;

  const int tid  = threadIdx.x;
  const int lane = tid & 63;
  const int w    = tid >> 6;       // 0..7
  const int wr   = w >> 2;         // 0..1 : M interleave
  const int wc   = w & 3;          // 0..3 : N interleave

  const u16* __restrict__ xrow = xb + (size_t)b * XPBP;
  const u16* __restrict__ Wg   = wb + (size_t)woff + (size_t)chblk * BN * Kp;

  // stage one 128x64 half: linear LDS dest (wave-uniform base), inverse-swizzled src
  auto STAGE = [&](const u16* src, int stride, u16* buf, int half) {
    #pragma unroll
    for (int i = 0; i < 2; i++) {
      int c = i * 512 + w * 64 + lane;                  // chunk 0..1023
      int row128 = c >> 3;
      int colb = ((c & 7) * 16) ^ ((row128 & 7) << 4);  // inverse swizzle (involution)
      gload_lds16(src + (size_t)(half * 128 + row128) * stride + (colb >> 1),
                  buf + half * 8192 + i * 4096 + w * 512);
    }
  };

  // swizzled fragment read: group grp (16 rows), ksub k
  auto FR = [&](const u16* buf, int grp, int k) -> bf16x8 {
    int row  = grp * 16 + (lane & 15);
    int colb = (k * 64 + ((lane >> 4) << 4)) ^ ((lane & 7) << 4);  // row&7 == lane&7
    return *(const bf16x8*)(buf + row * 64 + (colb >> 1));
  };

  f32x4 acc[8][4];
  #pragma unroll
  for (int mi = 0; mi < 8; mi++)
    #pragma unroll
    for (int ni = 0; ni < 4; ni++)
      acc[mi][ni] = (f32x4){0.f, 0.f, 0.f, 0.f};

  bf16x8 afrA[4][2];      // A-half-0 frags (region I MFMAs)
  bf16x8 afrB[4][2];      // A-half-1 frags (region II MFMAs)
  bf16x8 bfr[2][2][2];    // [nh][b2][k2]
  float rmax[4] = { -1e30f, -1e30f, -1e30f, -1e30f };

  auto FOLD = [&](int ttf) {
    #pragma unroll
    for (int mi = 0; mi < 8; mi++) {
      int tb = ttf * 256 + (mi * 2 + wr) * 16 + ((lane >> 4) << 2);
      #pragma unroll
      for (int r = 0; r < 4; r++) {
        bool ok = (tb + r) < Lt;
        #pragma unroll
        for (int ni = 0; ni < 4; ni++)
          if (ok) rmax[ni] = fmaxf(rmax[ni], acc[mi][ni][r]);
      }
      #pragma unroll
      for (int ni = 0; ni < 4; ni++)
        acc[mi][ni] = (f32x4){0.f, 0.f, 0.f, 0.f};
    }
  };

#define READ_A(DST, BUF, MH) do {                                             \
    _Pragma("unroll")                                                         \
    for (int a2 = 0; a2 < 4; a2++) {                                          \
      _Pragma("unroll")                                                       \
      for (int k2 = 0; k2 < 2; k2++)                                          \
        DST[a2][k2] = FR(BUF, ((MH)*4 + a2) * 2 + wr, k2);                    \
    }                                                                         \
  } while (0)

#define READ_B(NH, BUF) do {                                                  \
    _Pragma("unroll")                                                         \
    for (int b2 = 0; b2 < 2; b2++) {                                          \
      _Pragma("unroll")                                                       \
      for (int k2 = 0; k2 < 2; k2++)                                          \
        bfr[NH][b2][k2] = FR(BUF, ((NH)*2 + b2) * 4 + wc, k2);                \
    }                                                                         \
  } while (0)

#define MFMAQ(MH, NH, A) do {                                                 \
    __builtin_amdgcn_s_setprio(1);                                            \
    _Pragma("unroll")                                                         \
    for (int a2 = 0; a2 < 4; a2++)                                            \
      _Pragma("unroll")                                                       \
      for (int b2 = 0; b2 < 2; b2++)                                          \
        _Pragma("unroll")                                                     \
        for (int k2 = 0; k2 < 2; k2++)                                        \
          acc[(MH)*4 + a2][(NH)*2 + b2] =                                     \
            __builtin_amdgcn_mfma_f32_16x16x32_bf16(A[a2][k2],                \
              bfr[NH][b2][k2], acc[(MH)*4 + a2][(NH)*2 + b2], 0, 0, 0);       \
    __builtin_amdgcn_s_setprio(0);                                            \
  } while (0)

  const int NT = 4 * nks;    // 40 / 60 / 80 (always even)
  int tt = 0, ks = 0;

  // ---- prologue: tile0 -> buf0, order [A-h0, B-h0, B-h1, A-h1] ----
  STAGE(xrow, CINP, A0s, 0);
  STAGE(Wg,   Kp,   B0s, 0);
  STAGE(Wg,   Kp,   B0s, 1);
  STAGE(xrow, CINP, A0s, 1);
  VM2;                       // retire A0,B0,B1 (A-h1 outstanding)
  BAR();

  // ---- steady K-loop (tiles 0 .. NT-2), 2 barriers/step ----
  for (int s = 0; s < NT - 1; s++) {
    int ks2 = ks + 1, tt2 = tt;
    if (ks2 == nks) { ks2 = 0; tt2++; }
    const u16* sA = xrow + (size_t)tt2 * (256 * CINP) + ks2 * 64;
    const u16* sB = Wg + ks2 * 64;
    u16* cA = (s & 1) ? A1s : A0s;
    u16* cB = (s & 1) ? B1s : B0s;
    u16* nA = (s & 1) ? A0s : A1s;
    u16* nB = (s & 1) ? B0s : B1s;

    // ---- region I = [ph1+ph2]: start-reads certified at prev region-II end
    READ_A(afrA, cA, 0);
    READ_B(0, cB);
    STAGE(sA, CINP, nA, 0);
    MFMAQ(0, 0, afrA);
    READ_B(1, cB);
    STAGE(sB, Kp, nB, 0);
    MFMAQ(0, 1, afrA);
    VM4;                     // retire prev a1 -> certify cA-h1 (a0,b0 stay in flight)
    BAR();
    // ---- region II = [ph3+ph4]
    READ_A(afrB, cA, 1);     // cA-h1 (certified at region-I end)
    STAGE(sB, Kp, nB, 1);
    MFMAQ(1, 0, afrB);
    STAGE(sA, CINP, nA, 1);
    MFMAQ(1, 1, afrB);
    VM2;                     // retire a0,b0,b1 -> certify next region-I reads
    BAR();

    if (++ks == nks) { FOLD(tt); ks = 0; tt++; }
  }

  // ---- peeled last step (reads buf1; no staging; drain to 0) ----
  {
    u16* cA = A1s;           // NT even -> last step parity 1
    u16* cB = B1s;
    READ_A(afrA, cA, 0);     // certified at last steady region-II end
    READ_B(0, cB);
    MFMAQ(0, 0, afrA);
    READ_B(1, cB);
    MFMAQ(0, 1, afrA);
    VM0;                     // retire a1 -> certify cA-h1
    BAR();
    READ_A(afrB, cA, 1);
    MFMAQ(1, 0, afrB);
    MFMAQ(1, 1, afrB);
    FOLD(tt);
  }
#undef READ_A
#undef READ_B
#undef MFMAQ

  // ---- epilogue: intra-wave max, cross-wave (wr pair) combine, bias+relu ----
  float cv[4];
  #pragma unroll
  for (int ni = 0; ni < 4; ni++) {
    float v = rmax[ni];
    v = fmaxf(v, __shfl_xor(v, 16));
    v = fmaxf(v, __shfl_xor(v, 32));
    cv[ni] = v;
  }
  __syncthreads();                    // full drain; smem reusable
  float* red = (float*)smem;          // 512 floats: [wr][gn*16 + col]
  if (lane < 16) {
    #pragma unroll
    for (int ni = 0; ni < 4; ni++)
      red[wr * 256 + (ni * 4 + wc) * 16 + lane] = cv[ni];
  }
  __syncthreads();
  const float* bias = (g == 0) ? b2v : (g == 1) ? b3v : b4v;
  if (tid < 256) {
    float v = fmaxf(red[tid], red[256 + tid]);
    int ch = chblk * BN + tid;
    if (ch < NCH) {
      int n = ch / ODIM, o = ch - n * ODIM;
      out[b * (ODIM * 180) + o * 180 + g * 60 + n] = fmaxf(v + bias[ch], 0.f);
    }
  }
}

extern "C" void kernel_launch(void* const* d_in, const int* in_sizes, int n_in,
                              void* d_out, int out_size, void* d_ws, size_t ws_size,
                              hipStream_t stream) {
  const float* x  = (const float*)d_in[0];
  const float* W2 = (const float*)d_in[1];
  const float* b2 = (const float*)d_in[2];
  const float* W3 = (const float*)d_in[3];
  const float* b3 = (const float*)d_in[4];
  const float* W4 = (const float*)d_in[5];
  const float* b4 = (const float*)d_in[6];
  float* out = (float*)d_out;

  u16* xb = (u16*)d_ws;            // XELP bf16 (10.5 MB)
  u16* wb = xb + XELP;             // NCHP*(640+960+1280) bf16 (35.4 MB)

  prep_kernel<<<3 * NCHP + XELP / (256 * 8), 256, 0, stream>>>(x, W2, W3, W4, xb, wb);
  gemm_max_kernel<<<dim3(1152), 512, 0, stream>>>(xb, wb, b2, b3, b4, out);
}

// Round 15
// 480.567 us; speedup vs baseline: 1.0234x; 1.0234x over previous
//
#include <hip/hip_runtime.h>
#include <cstdint>
#include <cstddef>

typedef unsigned short u16;
typedef unsigned int   u32;
typedef __attribute__((ext_vector_type(8))) short bf16x8;
typedef __attribute__((ext_vector_type(4))) float f32x4;

#define NB   16
#define LL   1024
#define CIN  300
#define CINP 320              /* padded channels: rows 640B, 16B aligned */
#define XPBP (LL*CINP)        /* 327680 elems per batch */
#define XELP (NB*XPBP)        /* 5242880 */
#define NCH  6000
#define NCHP 6144             /* padded to 24*256 */
#define ODIM 100

#define BM 256
#define BN 256
#define BK 64

__device__ __forceinline__ u16 f2bf(float f) {
  union { float f; u32 u; } v; v.f = f;
  return (u16)((v.u + 0x7FFFu + ((v.u >> 16) & 1u)) >> 16);   // RNE, inputs finite
}

typedef __attribute__((address_space(1))) const unsigned int gu32;
typedef __attribute__((address_space(3))) unsigned int lu32;
__device__ __forceinline__ void gload_lds16(const void* g, void* l) {
  __builtin_amdgcn_global_load_lds((gu32*)g, (lu32*)l, 16, 0, 0);
}

#define BAR() asm volatile("s_barrier" ::: "memory")
#define VM2  asm volatile("s_waitcnt vmcnt(2)" ::: "memory")
#define VM0  asm volatile("s_waitcnt vmcnt(0)" ::: "memory")

// ---- merged prep: repack W (blocks 0..18431) + cvt x (blocks 18432..20991)
__global__ void prep_kernel(const float* __restrict__ x,
                            const float* __restrict__ W2, const float* __restrict__ W3,
                            const float* __restrict__ W4,
                            u16* __restrict__ xb, u16* __restrict__ wb) {
  int bid = blockIdx.x;
  if (bid < 3 * NCHP) {
    // W[n,o,c,j] f32 -> Wb[no][kp = j*320 + c] bf16 (zeros c>=300, no>=6000)
    int g  = bid / NCHP;
    int no = bid - g * NCHP;                   // 0..6143
    int kk = g + 2;
    int Kp = kk * CINP;
    int woff = (g == 0) ? 0 : (g == 1) ? NCHP*640 : NCHP*(640+960);
    const float* W = (g == 0) ? W2 : (g == 1) ? W3 : W4;
    u16* dst = wb + (size_t)woff + (size_t)no * Kp;
    const float* src = W + (size_t)no * (CIN * kk);
    for (int kp = threadIdx.x; kp < Kp; kp += 256) {
      int j = kp / CINP, c = kp - j * CINP;
      u16 v = 0;
      if (no < NCH && c < CIN) v = f2bf(src[c * kk + j]);
      dst[kp] = v;
    }
  } else {
    // x [16,1024,300] f32 -> xb [16,1024,320] bf16 (zero-pad channels)
    int i8 = ((bid - 3 * NCHP) * 256 + threadIdx.x) * 8;   // 2560 blocks
    int row = i8 / CINP;
    int col = i8 - row * CINP;
    const float* src = x + (size_t)row * CIN + col;
    u16 e[8];
    if (col + 8 <= CIN) {
      float4 a = *(const float4*)src;
      float4 b = *(const float4*)(src + 4);
      e[0]=f2bf(a.x); e[1]=f2bf(a.y); e[2]=f2bf(a.z); e[3]=f2bf(a.w);
      e[4]=f2bf(b.x); e[5]=f2bf(b.y); e[6]=f2bf(b.z); e[7]=f2bf(b.w);
    } else {
      #pragma unroll
      for (int j = 0; j < 8; j++)
        e[j] = (col + j < CIN) ? f2bf(src[j]) : (u16)0;
    }
    uint4 o;
    o.x = (u32)e[0] | ((u32)e[1] << 16);
    o.y = (u32)e[2] | ((u32)e[3] << 16);
    o.z = (u32)e[4] | ((u32)e[5] << 16);
    o.w = (u32)e[6] | ((u32)e[7] << 16);
    *(uint4*)(xb + i8) = o;
  }
}

// ---- fused GEMM + running-max + bias + relu ------------------------------
// 256^2 8-phase tail-read schedule, 3 barriers/K-step (r13 optimum: ph2-end
// barrier deleted — it certified nothing; ph3 has no ds_reads, and all WAR
// gaps in the merged [ph2+ph3] region are >= 2 barriers).  Certification:
//   ph1-end vmcnt(2)+BAR -> {cur A1}  certified for ph2-tail read
//   ph3-end vmcnt(2)+BAR -> {nA0,nB0} certified for ph4-tail reads
//   ph4-end vmcnt(2)+BAR -> {nB1}     certified for next ph1-tail read
__global__ __launch_bounds__(512, 1)
void gemm_max_kernel(const u16* __restrict__ xb, const u16* __restrict__ wb,
                     const float* __restrict__ b2v, const float* __restrict__ b3v,
                     const float* __restrict__ b4v, float* __restrict__ out) {
  // LPT remap: ids 0..383 -> g=2, 384..767 -> g=1, 768..1151 -> g=0
  const int id    = blockIdx.x;
  const int g     = 2 - (id / 384);
  const int id2   = id % 384;
  const int b     = id2 / 24;      // 0..15
  const int chblk = id2 % 24;      // 0..23
  const int Kp    = (g + 2) * CINP;                 // 640 / 960 / 1280
  const int nks   = Kp >> 6;                        // 10 / 15 / 20
  const int woff  = (g == 0) ? 0 : (g == 1) ? NCHP*640 : NCHP*(640+960);
  const int Lt    = LL - (g + 2) + 1;

  __shared__ __align__(16) u16 smem[4 * 16384];     // 128 KiB
  u16* A0s = smem;
  u16* B0s = smem + 16384;
  u16* A1s = smem + 32768;
  u16* B1s = smem + 49152;

  const int tid  = threadIdx.x;
  const int lane = tid & 63;
  const int w    = tid >> 6;       // 0..7
  const int wr   = w >> 2;         // 0..1 : M interleave
  const int wc   = w & 3;          // 0..3 : N interleave

  const u16* __restrict__ xrow = xb + (size_t)b * XPBP;
  const u16* __restrict__ Wg   = wb + (size_t)woff + (size_t)chblk * BN * Kp;

  // stage one 128x64 half: linear LDS dest (wave-uniform base), inverse-swizzled src
  auto STAGE = [&](const u16* src, int stride, u16* buf, int half) {
    #pragma unroll
    for (int i = 0; i < 2; i++) {
      int c = i * 512 + w * 64 + lane;                  // chunk 0..1023
      int row128 = c >> 3;
      int colb = ((c & 7) * 16) ^ ((row128 & 7) << 4);  // inverse swizzle (involution)
      gload_lds16(src + (size_t)(half * 128 + row128) * stride + (colb >> 1),
                  buf + half * 8192 + i * 4096 + w * 512);
    }
  };

  // swizzled fragment read: group grp (16 rows), ksub k
  auto FR = [&](const u16* buf, int grp, int k) -> bf16x8 {
    int row  = grp * 16 + (lane & 15);
    int colb = (k * 64 + ((lane >> 4) << 4)) ^ ((lane & 7) << 4);  // row&7 == lane&7
    return *(const bf16x8*)(buf + row * 64 + (colb >> 1));
  };

  f32x4 acc[8][4];
  #pragma unroll
  for (int mi = 0; mi < 8; mi++)
    #pragma unroll
    for (int ni = 0; ni < 4; ni++)
      acc[mi][ni] = (f32x4){0.f, 0.f, 0.f, 0.f};

  bf16x8 afrA[4][2];      // A-half-0 frags (used ph1, ph2)
  bf16x8 afrB[4][2];      // A-half-1 frags (used ph3, ph4)
  bf16x8 bfr[2][2][2];    // [nh][b2][k2]
  float rmax[4] = { -1e30f, -1e30f, -1e30f, -1e30f };

  auto FOLD = [&](int ttf) {
    #pragma unroll
    for (int mi = 0; mi < 8; mi++) {
      int tb = ttf * 256 + (mi * 2 + wr) * 16 + ((lane >> 4) << 2);
      #pragma unroll
      for (int r = 0; r < 4; r++) {
        bool ok = (tb + r) < Lt;
        #pragma unroll
        for (int ni = 0; ni < 4; ni++)
          if (ok) rmax[ni] = fmaxf(rmax[ni], acc[mi][ni][r]);
      }
      #pragma unroll
      for (int ni = 0; ni < 4; ni++)
        acc[mi][ni] = (f32x4){0.f, 0.f, 0.f, 0.f};
    }
  };

#define READ_A(DST, BUF, MH) do {                                             \
    _Pragma("unroll")                                                         \
    for (int a2 = 0; a2 < 4; a2++) {                                          \
      _Pragma("unroll")                                                       \
      for (int k2 = 0; k2 < 2; k2++)                                          \
        DST[a2][k2] = FR(BUF, ((MH)*4 + a2) * 2 + wr, k2);                    \
    }                                                                         \
  } while (0)

#define READ_B(NH, BUF) do {                                                  \
    _Pragma("unroll")                                                         \
    for (int b2 = 0; b2 < 2; b2++) {                                          \
      _Pragma("unroll")                                                       \
      for (int k2 = 0; k2 < 2; k2++)                                          \
        bfr[NH][b2][k2] = FR(BUF, ((NH)*2 + b2) * 4 + wc, k2);                \
    }                                                                         \
  } while (0)

#define MFMAQ(MH, NH, A) do {                                                 \
    __builtin_amdgcn_s_setprio(1);                                            \
    _Pragma("unroll")                                                         \
    for (int a2 = 0; a2 < 4; a2++)                                            \
      _Pragma("unroll")                                                       \
      for (int b2 = 0; b2 < 2; b2++)                                          \
        _Pragma("unroll")                                                     \
        for (int k2 = 0; k2 < 2; k2++)                                        \
          acc[(MH)*4 + a2][(NH)*2 + b2] =                                     \
            __builtin_amdgcn_mfma_f32_16x16x32_bf16(A[a2][k2],                \
              bfr[NH][b2][k2], acc[(MH)*4 + a2][(NH)*2 + b2], 0, 0, 0);       \
    __builtin_amdgcn_s_setprio(0);                                            \
  } while (0)

  const int NT = 4 * nks;    // 40 / 60 / 80 (always even)
  int tt = 0, ks = 0;

  // ---- prologue: tile0 -> buf0, order [A-h0, B-h0, B-h1, A-h1] ----
  STAGE(xrow, CINP, A0s, 0);
  STAGE(Wg,   Kp,   B0s, 0);
  STAGE(Wg,   Kp,   B0s, 1);
  STAGE(xrow, CINP, A0s, 1);
  VM2;                       // A-h0, B-h0, B-h1 certified (A-h1 outstanding)
  BAR();
  READ_A(afrA, A0s, 0);
  READ_B(0, B0s);

  // ---- steady K-loop (tiles 0 .. NT-2), 3 barriers/step ----
  for (int s = 0; s < NT - 1; s++) {
    int ks2 = ks + 1, tt2 = tt;
    if (ks2 == nks) { ks2 = 0; tt2++; }
    const u16* sA = xrow + (size_t)tt2 * (256 * CINP) + ks2 * 64;
    const u16* sB = Wg + ks2 * 64;
    u16* cA = (s & 1) ? A1s : A0s;
    u16* cB = (s & 1) ? B1s : B0s;
    u16* nA = (s & 1) ? A0s : A1s;
    u16* nB = (s & 1) ? B0s : B1s;

    // ph1
    STAGE(sA, CINP, nA, 0);
    MFMAQ(0, 0, afrA);
    READ_B(1, cB);           // cur B-h1 (certified at prev ph4-end)
    VM2;                     // certify cur A-h1 (for ph2 read)
    BAR();
    // ph2 + ph3 merged (ph2-end barrier deleted: certified reads unchanged,
    // WAR gaps >= 2 barriers, per-wave DMA chunks disjoint)
    STAGE(sB, Kp, nB, 0);
    MFMAQ(0, 1, afrA);
    READ_A(afrB, cA, 1);     // cur A-h1 (certified at ph1-end)
    STAGE(sB, Kp, nB, 1);
    MFMAQ(1, 0, afrB);
    VM2;                     // certify nA-h0, nB-h0 (for ph4 reads)
    BAR();
    // ph4
    STAGE(sA, CINP, nA, 1);
    MFMAQ(1, 1, afrB);
    READ_A(afrA, nA, 0);     // next A-h0 (certified at ph3-end)
    READ_B(0, nB);           // next B-h0 (certified at ph3-end)
    VM2;                     // certify nB-h1 (for next ph1 read)
    BAR();

    if (++ks == nks) { FOLD(tt); ks = 0; tt++; }
  }

  // ---- peeled last tile (reads buf1; no staging; drain to 0) ----
  {
    MFMAQ(0, 0, afrA);
    READ_B(1, B1s);          // certified at last steady ph4-end
    VM0;                     // certify A1s (last outstanding stage)
    BAR();
    MFMAQ(0, 1, afrA);
    READ_A(afrB, A1s, 1);    // A-h1 (certified at VM0 + BAR)
    MFMAQ(1, 0, afrB);
    MFMAQ(1, 1, afrB);
    FOLD(tt);
  }
#undef READ_A
#undef READ_B
#undef MFMAQ

  // ---- epilogue: intra-wave max, cross-wave (wr pair) combine, bias+relu ----
  float cv[4];
  #pragma unroll
  for (int ni = 0; ni < 4; ni++) {
    float v = rmax[ni];
    v = fmaxf(v, __shfl_xor(v, 16));
    v = fmaxf(v, __shfl_xor(v, 32));
    cv[ni] = v;
  }
  __syncthreads();                    // full drain; smem reusable
  float* red = (float*)smem;          // 512 floats: [wr][gn*16 + col]
  if (lane < 16) {
    #pragma unroll
    for (int ni = 0; ni < 4; ni++)
      red[wr * 256 + (ni * 4 + wc) * 16 + lane] = cv[ni];
  }
  __syncthreads();
  const float* bias = (g == 0) ? b2v : (g == 1) ? b3v : b4v;
  if (tid < 256) {
    float v = fmaxf(red[tid], red[256 + tid]);
    int ch = chblk * BN + tid;
    if (ch < NCH) {
      int n = ch / ODIM, o = ch - n * ODIM;
      out[b * (ODIM * 180) + o * 180 + g * 60 + n] = fmaxf(v + bias[ch], 0.f);
    }
  }
}

extern "C" void kernel_launch(void* const* d_in, const int* in_sizes, int n_in,
                              void* d_out, int out_size, void* d_ws, size_t ws_size,
                              hipStream_t stream) {
  const float* x  = (const float*)d_in[0];
  const float* W2 = (const float*)d_in[1];
  const float* b2 = (const float*)d_in[2];
  const float* W3 = (const float*)d_in[3];
  const float* b3 = (const float*)d_in[4];
  const float* W4 = (const float*)d_in[5];
  const float* b4 = (const float*)d_in[6];
  float* out = (float*)d_out;

  u16* xb = (u16*)d_ws;            // XELP bf16 (10.5 MB)
  u16* wb = xb + XELP;             // NCHP*(640+960+1280) bf16 (35.4 MB)

  prep_kernel<<<3 * NCHP + XELP / (256 * 8), 256, 0, stream>>>(x, W2, W3, W4, xb, wb);
  gemm_max_kernel<<<dim3(1152), 512, 0, stream>>>(xb, wb, b2, b3, b4, out);
}